// Round 3
// baseline (889.979 us; speedup 1.0000x reference)
//
#include <hip/hip_runtime.h>
#include <math.h>

#define HDIM 70
#define HPAD 72
#define HP2 80        // h padded to 4 chunks of 20 (16B-aligned)
#define GATES 280
#define NG 288        // gates padded to 18*16
#define TLEN 512
#define BATCH 128
#define CDIM 1104
#define KW 1152       // K padded to 18*64
#define ROWS 65536    // BATCH*TLEN

// ws layout (float offsets)
#define OFF_WRNT  0          // 70*1104 fp32 transposed [h][c] -> 77280 (round 77312)
#define OFF_BIAS  77312      // 280 fp32 (round 320)
#define OFF_WCT   77632      // 288*1152 bf16 = 165888 floats
#define OFF_XG    243520     // 65536*280 bf16 = 9175040 floats
#define OFF_HOUT  9418560    // 65536*72 fp32 = 4718592
#define OFF_EN    14137152   // 65536 fp32

typedef short short8 __attribute__((ext_vector_type(8)));
typedef float f32x4 __attribute__((ext_vector_type(4)));

__device__ __forceinline__ unsigned short f2bf(float f) {
    unsigned int u = __float_as_uint(f);
    u = (u + 0x7fffu + ((u >> 16) & 1u)) >> 16;
    return (unsigned short)u;
}
__device__ __forceinline__ float bf2f(unsigned short s) {
    return __uint_as_float(((unsigned int)s) << 16);
}

// ---------------- K1: row renorm of embed_w -> TRANSPOSED wrnT[h][c] ----------------
__global__ __launch_bounds__(64) void k_renorm(const float* __restrict__ w,
                                               float* __restrict__ wrnT) {
    const int row = blockIdx.x;   // c index 0..1103
    const int lane = threadIdx.x;
    const float* wr = w + row * HDIM;
    float v0 = wr[lane];
    float v1 = (lane < 6) ? wr[64 + lane] : 0.0f;
    float ss = v0 * v0 + v1 * v1;
    #pragma unroll
    for (int off = 32; off > 0; off >>= 1) ss += __shfl_down(ss, off);
    float tot = __shfl(ss, 0);
    float n = sqrtf(tot);
    float scale = (n > 1.0f) ? 1.0f / (n + 1e-7f) : 1.0f;
    wrnT[lane * CDIM + row] = v0 * scale;
    if (lane < 6) wrnT[(64 + lane) * CDIM + row] = v1 * scale;
}

// ---------------- K2: WcT[n][k] = sum_h w_ih[n][h]*wrnT[h][k], bf16, padded ----------------
__global__ __launch_bounds__(256) void k_prep(const float* __restrict__ wrnT,
                                              const float* __restrict__ w_ih,
                                              const float* __restrict__ b_ih,
                                              const float* __restrict__ b_hh,
                                              unsigned short* __restrict__ wcT,
                                              float* __restrict__ bias) {
    const int n = blockIdx.x;      // 0..287
    const int tid = threadIdx.x;
    float wr[HDIM];
    if (n < GATES) {
        #pragma unroll
        for (int h = 0; h < HDIM; ++h) wr[h] = w_ih[n * HDIM + h];
        if (tid == 0) bias[n] = b_ih[n] + b_hh[n];
    } else {
        #pragma unroll
        for (int h = 0; h < HDIM; ++h) wr[h] = 0.0f;
    }
    for (int c = tid; c < KW; c += 256) {
        float a = 0.0f;
        if (n < GATES && c < CDIM) {
            #pragma unroll
            for (int h = 0; h < HDIM; ++h) a += wr[h] * wrnT[h * CDIM + c];
        }
        wcT[(size_t)n * KW + c] = f2bf(a);
    }
}

// ---------------- K3: xg = x @ Wc + bias  (bf16 MFMA, M=65536,N=288,K=1152) ----------------
// output layout: xg[row*280 + unit*4 + comp]  (gate-interleaved for k_lstm)
__global__ __launch_bounds__(256, 2) void k_xg_gemm(const float* __restrict__ x,
                                                    const unsigned short* __restrict__ wcT,
                                                    const float* __restrict__ bias,
                                                    unsigned short* __restrict__ xg) {
    __shared__ __align__(16) unsigned short A_lds[128 * 72];  // [row][k] stride 72
    __shared__ __align__(16) unsigned short B_lds[NG * 72];   // [n][k]   stride 72
    const int tid = threadIdx.x;
    const int lane = tid & 63;
    const int w = tid >> 6;
    const int mh = (w >> 1) * 64;     // wave M-half: 0 or 64
    const int nh = (w & 1) * 144;     // wave N-half: 0 or 144 (9 n-tiles)
    const int l15 = lane & 15;
    const int lq = lane >> 4;
    const size_t rbase = (size_t)blockIdx.x * 128;

    f32x4 acc[4][9];
    #pragma unroll
    for (int mt = 0; mt < 4; ++mt)
        #pragma unroll
        for (int nt = 0; nt < 9; ++nt) acc[mt][nt] = (f32x4){0.f, 0.f, 0.f, 0.f};

    const int r_st = tid >> 1;
    const int kh_st = (tid & 1) * 32;

    for (int kc = 0; kc < 18; ++kc) {
        const int k0 = kc * 64;
        // stage A: 128 rows x 64 k fp32 -> bf16
        {
            const float* xr = x + (rbase + r_st) * (size_t)CDIM + k0 + kh_st;
            unsigned short* dst = &A_lds[r_st * 72 + kh_st];
            #pragma unroll
            for (int qq = 0; qq < 8; ++qq) {
                const int kk = k0 + kh_st + qq * 4;
                float4 v = make_float4(0.f, 0.f, 0.f, 0.f);
                if (kk < CDIM) v = *(const float4*)(xr + qq * 4);
                unsigned int lo = (unsigned int)f2bf(v.x) | ((unsigned int)f2bf(v.y) << 16);
                unsigned int hi = (unsigned int)f2bf(v.z) | ((unsigned int)f2bf(v.w) << 16);
                uint2 pv; pv.x = lo; pv.y = hi;
                *(uint2*)&dst[qq * 4] = pv;
            }
        }
        // stage B: 288 n x 64 k bf16 (already padded with zeros)
        {
            #pragma unroll
            for (int p = 0; p < 9; ++p) {
                const int cid = tid + p * 256;
                const int n = cid >> 3;
                const int ko = (cid & 7) * 8;
                uint4 v = *(const uint4*)(wcT + (size_t)n * KW + k0 + ko);
                *(uint4*)&B_lds[n * 72 + ko] = v;
            }
        }
        __syncthreads();
        #pragma unroll
        for (int ks = 0; ks < 2; ++ks) {
            short8 a[4];
            short8 bfr[9];
            #pragma unroll
            for (int mt = 0; mt < 4; ++mt)
                a[mt] = *(const short8*)&A_lds[(mh + mt * 16 + l15) * 72 + ks * 32 + lq * 8];
            #pragma unroll
            for (int nt = 0; nt < 9; ++nt)
                bfr[nt] = *(const short8*)&B_lds[(nh + nt * 16 + l15) * 72 + ks * 32 + lq * 8];
            #pragma unroll
            for (int mt = 0; mt < 4; ++mt)
                #pragma unroll
                for (int nt = 0; nt < 9; ++nt)
                    acc[mt][nt] = __builtin_amdgcn_mfma_f32_16x16x32_bf16(a[mt], bfr[nt], acc[mt][nt], 0, 0, 0);
        }
        __syncthreads();
    }
    // epilogue: + bias, store bf16 gate-interleaved. D: m=(lq*4+r), n=l15 within tile.
    #pragma unroll
    for (int nt = 0; nt < 9; ++nt) {
        const int n_g = nh + nt * 16 + l15;
        if (n_g >= GATES) continue;
        const float bv = bias[n_g];
        const int comp = n_g / 70;          // 0..3 (i,f,g,o)
        const int unit = n_g - comp * 70;   // 0..69
        const int col = unit * 4 + comp;
        #pragma unroll
        for (int mt = 0; mt < 4; ++mt) {
            #pragma unroll
            for (int r = 0; r < 4; ++r) {
                const size_t row = rbase + mh + mt * 16 + lq * 4 + r;
                xg[row * GATES + col] = f2bf(acc[mt][nt][r] + bv);
            }
        }
    }
}

// ---------------- K4: LSTM scan, split-K GEMV + fused cell ----------------
__device__ __forceinline__ float tanh_fast(float v) {
    v = fminf(fmaxf(v, -20.0f), 20.0f);
    float E = __expf(2.0f * v);
    return (E - 1.0f) / (E + 1.0f);
}
__device__ __forceinline__ float sigmoid_fast(float v) {
    return 1.0f / (1.0f + __expf(-v));
}

#define PF 8
__global__ __launch_bounds__(320) void k_lstm(const unsigned short* __restrict__ xg,
                                              const float* __restrict__ w_hh,
                                              float* __restrict__ hout) {
    __shared__ __align__(16) float h_lds[2][HP2];
    const int tid = threadIdx.x;
    const int b = blockIdx.x;
    const int q = tid >> 2;      // hidden unit 0..79 (70..79 dummy)
    const int c = tid & 3;       // k-chunk AND gate component (i,f,g,o)

    // weights: 4 gates {c*70+q for c=0..3} wait -- gates {v*70+q}, k-slice [20c,20c+20)
    float whh[4][20];
    #pragma unroll
    for (int v = 0; v < 4; ++v)
        #pragma unroll
        for (int kk = 0; kk < 20; ++kk) {
            const int k = 20 * c + kk;
            whh[v][kk] = (q < HDIM && k < HDIM) ? w_hh[(70 * v + q) * HDIM + k] : 0.0f;
        }

    if (tid < HP2) { h_lds[0][tid] = 0.0f; h_lds[1][tid] = 0.0f; }
    float c_reg = 0.0f;

    const unsigned short* xp = xg + (size_t)b * TLEN * GATES + (tid < GATES ? tid : 0);
    float xbuf[PF];
    #pragma unroll
    for (int i = 0; i < PF; ++i) xbuf[i] = bf2f(xp[(size_t)i * GATES]);
    __syncthreads();

    #pragma unroll 8
    for (int t = 0; t < TLEN; ++t) {
        const int slot = t & (PF - 1);
        const float xcur = xbuf[slot];
        xbuf[slot] = bf2f(xp[(size_t)((t + PF) & (TLEN - 1)) * GATES]);  // prefetch

        float acc[4] = {0.f, 0.f, 0.f, 0.f};
        const float4* hp = (const float4*)&h_lds[t & 1][20 * c];
        #pragma unroll
        for (int i5 = 0; i5 < 5; ++i5) {
            const float4 hv = hp[i5];
            #pragma unroll
            for (int v = 0; v < 4; ++v) {
                acc[v] += hv.x * whh[v][4 * i5];
                acc[v] += hv.y * whh[v][4 * i5 + 1];
                acc[v] += hv.z * whh[v][4 * i5 + 2];
                acc[v] += hv.w * whh[v][4 * i5 + 3];
            }
        }
        acc[c] += xcur;  // this lane's loaded xg is for component c

        // 4-lane butterfly all-reduce (bitwise-identical on all 4 lanes)
        #pragma unroll
        for (int v = 0; v < 4; ++v) {
            acc[v] += __shfl_xor(acc[v], 1);
            acc[v] += __shfl_xor(acc[v], 2);
        }

        const float iv = sigmoid_fast(acc[0]);
        const float fv = sigmoid_fast(acc[1]);
        const float gv = tanh_fast(acc[2]);
        const float ov = sigmoid_fast(acc[3]);
        c_reg = fv * c_reg + iv * gv;
        const float hn = ov * tanh_fast(c_reg);
        if (c == 0) {
            h_lds[(t & 1) ^ 1][q] = hn;
            if (q < HDIM) hout[((size_t)b * TLEN + t) * HPAD + q] = hn;
        }
        __syncthreads();
    }
}

// ---------------- K5a: attention energy ----------------
__global__ __launch_bounds__(256) void k_energy(const float* __restrict__ hout,
                                                const float* __restrict__ w1,
                                                const float* __restrict__ b1,
                                                const float* __restrict__ w2,
                                                const float* __restrict__ b2,
                                                float* __restrict__ energy) {
    const int lane = threadIdx.x & 63;
    const int wid = blockIdx.x * 4 + (threadIdx.x >> 6);
    float w1r[HPAD];
    #pragma unroll
    for (int cc = 0; cc < HDIM; ++cc) w1r[cc] = w1[lane * HDIM + cc];
    w1r[70] = w1r[71] = 0.0f;
    const float b1v = b1[lane];
    const float w2v = w2[lane];
    const float b2v = b2[0];
    for (int row = wid; row < ROWS; row += 4096) {
        const float4* rp = (const float4*)(hout + (size_t)row * HPAD);
        float a0 = 0.f, a1 = 0.f, a2 = 0.f, a3 = 0.f;
        #pragma unroll
        for (int jj = 0; jj < 18; ++jj) {
            float4 v = rp[jj];
            a0 += v.x * w1r[4 * jj];
            a1 += v.y * w1r[4 * jj + 1];
            a2 += v.z * w1r[4 * jj + 2];
            a3 += v.w * w1r[4 * jj + 3];
        }
        float hid = fmaxf((a0 + a1) + (a2 + a3) + b1v, 0.0f) * w2v;
        #pragma unroll
        for (int off = 32; off > 0; off >>= 1) hid += __shfl_down(hid, off);
        if (lane == 0) energy[row] = hid + b2v;
    }
}

// ---------------- K5b: softmax-pool + FC + softmax ----------------
__global__ __launch_bounds__(128) void k_pool(const float* __restrict__ hout,
                                              const float* __restrict__ energy,
                                              const float* __restrict__ fc_w,
                                              const float* __restrict__ fc_b,
                                              float* __restrict__ outp) {
    __shared__ float red[128];
    __shared__ float wexp[TLEN];
    __shared__ float pooledL[HDIM];
    const int tid = threadIdx.x;
    const int b = blockIdx.x;
    float v[4];
    #pragma unroll
    for (int k = 0; k < 4; ++k) v[k] = energy[b * TLEN + tid + 128 * k];
    float m = fmaxf(fmaxf(v[0], v[1]), fmaxf(v[2], v[3]));
    red[tid] = m; __syncthreads();
    for (int s = 64; s > 0; s >>= 1) {
        if (tid < s) red[tid] = fmaxf(red[tid], red[tid + s]);
        __syncthreads();
    }
    const float M = red[0]; __syncthreads();
    float s4 = 0.f;
    #pragma unroll
    for (int k = 0; k < 4; ++k) {
        float ex = __expf(v[k] - M);
        wexp[tid + 128 * k] = ex;
        s4 += ex;
    }
    red[tid] = s4; __syncthreads();
    for (int s = 64; s > 0; s >>= 1) {
        if (tid < s) red[tid] += red[tid + s];
        __syncthreads();
    }
    const float rinv = 1.0f / red[0];
    if (tid < HDIM) {
        float a0 = 0.f, a1 = 0.f, a2 = 0.f, a3 = 0.f;
        const float* hp = hout + (size_t)b * TLEN * HPAD + tid;
        for (int s = 0; s < TLEN; s += 4) {
            a0 += wexp[s]     * hp[(size_t)(s)     * HPAD];
            a1 += wexp[s + 1] * hp[(size_t)(s + 1) * HPAD];
            a2 += wexp[s + 2] * hp[(size_t)(s + 2) * HPAD];
            a3 += wexp[s + 3] * hp[(size_t)(s + 3) * HPAD];
        }
        pooledL[tid] = ((a0 + a1) + (a2 + a3)) * rinv;
    }
    __syncthreads();
    if (tid == 0) {
        float l[3];
        #pragma unroll
        for (int i = 0; i < 3; ++i) {
            float a = fc_b[i];
            for (int h = 0; h < HDIM; ++h) a += fc_w[i * HDIM + h] * pooledL[h];
            l[i] = a;
        }
        float m3 = fmaxf(l[0], fmaxf(l[1], l[2]));
        float e0 = __expf(l[0] - m3), e1 = __expf(l[1] - m3), e2 = __expf(l[2] - m3);
        float rs = 1.0f / (e0 + e1 + e2);
        outp[b * 3 + 0] = e0 * rs;
        outp[b * 3 + 1] = e1 * rs;
        outp[b * 3 + 2] = e2 * rs;
    }
}

extern "C" void kernel_launch(void* const* d_in, const int* in_sizes, int n_in,
                              void* d_out, int out_size, void* d_ws, size_t ws_size,
                              hipStream_t stream) {
    const float* x       = (const float*)d_in[0];
    const float* embed_w = (const float*)d_in[1];
    const float* w_ih    = (const float*)d_in[2];
    const float* w_hh    = (const float*)d_in[3];
    const float* b_ih    = (const float*)d_in[4];
    const float* b_hh    = (const float*)d_in[5];
    const float* aw1     = (const float*)d_in[6];
    const float* ab1     = (const float*)d_in[7];
    const float* aw2     = (const float*)d_in[8];
    const float* ab2     = (const float*)d_in[9];
    const float* fc_w    = (const float*)d_in[10];
    const float* fc_b    = (const float*)d_in[11];
    float* outp = (float*)d_out;
    float* ws = (float*)d_ws;

    float* wrnT = ws + OFF_WRNT;
    float* bias = ws + OFF_BIAS;
    unsigned short* wcT = (unsigned short*)(ws + OFF_WCT);
    unsigned short* xgp = (unsigned short*)(ws + OFF_XG);
    float* ho = ws + OFF_HOUT;
    float* en = ws + OFF_EN;

    k_renorm<<<CDIM, 64, 0, stream>>>(embed_w, wrnT);
    k_prep<<<NG, 256, 0, stream>>>(wrnT, w_ih, b_ih, b_hh, wcT, bias);
    k_xg_gemm<<<512, 256, 0, stream>>>(x, wcT, bias, xgp);
    k_lstm<<<BATCH, 320, 0, stream>>>(xgp, w_hh, ho);
    k_energy<<<1024, 256, 0, stream>>>(ho, aw1, ab1, aw2, ab2, en);
    k_pool<<<BATCH, 128, 0, stream>>>(ho, en, fc_w, fc_b, outp);
}